// Round 6
// baseline (699.610 us; speedup 1.0000x reference)
//
#include <hip/hip_runtime.h>

// Problem constants (reference: B,T,D,O = 16,1024,1024,10; T==D required)
#define BB 16
#define TT 1024
#define DD 1024
#define OO 10
#define ROWS 64
#define MAGIC 0x13579BDFu

// ---------------------------------------------------------------------------
// R19 (this): register-persistent X, re-budgeted to fit the compiler's OWN
// cap. R17/R18 evidence: for 512-thread blocks the toolchain pinned VGPR at
// 128 (= 512/4 waves-per-EU; launch_bounds 2nd arg behaved as CUDA
// min-BLOCKS, so (512,2) -> 16 waves/CU -> 128 cap) and spilled the
// 128-reg X tile (FETCH 421MB/WRITE 213MB scratch, 340us). Fix: 1024-thread
// (16-wave) blocks, where the forced cap is 128 and the tile is HALVED:
// each thread persists 2 rows x 8 float4 = 64 VGPR; acc[2][10]=20; total
// live ~110 < 128 -> no spill BY CONSTRUCTION, no launch-bounds semantics.
//
// Geometry: 64 rows/block, grid (16,16)=256 blocks = 1/CU (coop-launch
// co-residency for the flag sync). wv16=tid>>6: w=wv16&3 d-quarter,
// rq=wv16>>2 row-sixteenth; 8-lane groups, rows rq*16+g+8j (j=0..1),
// chunk c: d = w*256 + c*32 + l*4. FMA/reduction order identical to R16
// per row -> bitwise-same absmax. Phase A: u=exp((X.W^T+b)/10) (max-free
// softmax, scores sd~0.064). Batch-local sync: MAGIC flags in d_ws
// (re-poisoned each iter -> self-resetting; passed correctness in R17/R18)
// + __threadfence. Phase B: stage u slab 40KB -> LDS, Z in-block,
// out = X.u/Z with X from REGISTERS (second 64MB X sweep eliminated).
//
// Measured context: 2x41us 256MiB ws poison fills are UNCONDITIONAL -> 82us
// harness floor; R16 two-kernel = 37.2us addressable gemm (119.4 total).
//
// Refuted (do not retry): occupancy-hint bounds in EITHER direction (R2,
// R18), per-chunk LDS staging barriers (R6), grid.sync fusion (R8/R15:
// ~45us/sync), per-block softmax fold (R9), non-temporal X loads (R11),
// depth-4 prefetch (R12), ROWS=32 split (R13), 16-lane/256B chunks (R14),
// ws-avoidance (R15: fills stay), 512-thread register persistence (R17/R18).
// ---------------------------------------------------------------------------
__global__ __launch_bounds__(1024) void fused_persist(
    const float* __restrict__ X,     // (B,T,D)
    const float* __restrict__ W,     // (O,D)
    const float* __restrict__ bias,  // (O)
    float* __restrict__ out,         // (B,O,T)
    float* __restrict__ u,           // ws: (B,O,T) intermediate
    unsigned* __restrict__ flags)    // ws: [BB][16] batch-local sync flags
{
    __shared__ float4 sW4[OO * 256];      // 40 KB: W (phase A), u-slab (phase B)
    __shared__ float  part[4][ROWS][OO];  // 10 KB
    __shared__ float  zred[OO];

    const int b   = blockIdx.y;
    const int t0  = blockIdx.x * ROWS;
    const int tid = threadIdx.x;          // 0..1023

    // ---- stage W -> LDS (2560 float4 over 1024 threads) ----
    {
        const float4* src = (const float4*)W;
        if (tid < 512) {
#pragma unroll
            for (int c = 0; c < 5; ++c)
                sW4[c * 512 + tid] = src[c * 512 + tid];
        }
    }
    __syncthreads();

    const int wv16 = tid >> 6;       // wave 0..15
    const int w    = wv16 & 3;       // d quarter
    const int rq   = wv16 >> 2;      // row sixteenth (0..3)
    const int lane = tid & 63;
    const int l    = lane & 7;       // d-slice within row
    const int g    = lane >> 3;      // row group 0..7
    const int dofs = w * 256 + l * 4;
    const int rb   = rq * 16;

    const float* sWl = (const float*)sW4 + dofs;

    // ---- persistent X tile: 2 rows x 8 chunks = 16 float4 = 64 VGPR ----
    // c-major issue order = phase-A consumption order.
    float4 xr[8][2];
    {
        const float* xbase = X + ((size_t)b * TT + t0 + rb + g) * DD + dofs;
#pragma unroll
        for (int c = 0; c < 8; ++c)
#pragma unroll
            for (int j = 0; j < 2; ++j)
                xr[c][j] = *(const float4*)(xbase + (size_t)(8 * j) * DD + c * 32);
    }

    float acc[2][OO];
#pragma unroll
    for (int j = 0; j < 2; ++j)
#pragma unroll
        for (int o = 0; o < OO; ++o) acc[j][o] = 0.f;

    // ---- phase A: scores = X.W^T ----
#pragma unroll
    for (int c = 0; c < 8; ++c) {
        const float* wp = sWl + c * 32;
#pragma unroll
        for (int o = 0; o < OO; ++o) {
            const float4 wv = *(const float4*)(wp + o * DD);
#pragma unroll
            for (int j = 0; j < 2; ++j)
                acc[j][o] += xr[c][j].x * wv.x + xr[c][j].y * wv.y +
                             xr[c][j].z * wv.z + xr[c][j].w * wv.w;
        }
    }

    // cross-wave combine (8-lane tree, identical order to R16)
#pragma unroll
    for (int j = 0; j < 2; ++j) {
#pragma unroll
        for (int o = 0; o < OO; ++o) {
            float v = acc[j][o];
            v += __shfl_down(v, 4, 8);
            v += __shfl_down(v, 2, 8);
            v += __shfl_down(v, 1, 8);
            if (l == 0) part[w][rb + j * 8 + g][o] = v;
        }
    }
    __syncthreads();

    // epilogue A: u = exp((dot + bias)/O); 640 outputs, threads 0..639
    if (tid < ROWS * OO) {
        const int row = tid / OO;
        const int o   = tid % OO;
        float v = part[0][row][o] + part[1][row][o] +
                  part[2][row][o] + part[3][row][o];
        u[((size_t)b * OO + o) * TT + (t0 + row)] =
            __expf((v + bias[o]) * (1.0f / OO));
    }

    // ---- publish u, batch-local sync (16 blocks per batch) ----
    __threadfence();                 // u stores -> device scope
    __syncthreads();
    if (tid == 0)
        atomicExch(&flags[b * 16 + blockIdx.x], MAGIC);
    if (tid < 16) {
        while (atomicOr(&flags[b * 16 + tid], 0u) != MAGIC)
            __builtin_amdgcn_s_sleep(8);
    }
    __syncthreads();                 // all 16 flags seen -> whole block released
    __threadfence();                 // acquire side

    // ---- stage u slab (40 KB) -> LDS, overwriting W ----
    {
        const float4* src = (const float4*)(u + (size_t)b * OO * TT);
        if (tid < 512) {
#pragma unroll
            for (int c = 0; c < 5; ++c)
                sW4[c * 512 + tid] = src[c * 512 + tid];
        }
    }
    __syncthreads();

    // Z[b,o] = sum_t u (from slab). Wave wv16 = o (0..9).
    if (wv16 < OO) {
        float s = 0.f;
#pragma unroll
        for (int q = 0; q < 4; ++q) {
            const float4 v = sW4[wv16 * 256 + lane * 4 + q];
            s += v.x + v.y + v.z + v.w;
        }
#pragma unroll
        for (int off = 32; off > 0; off >>= 1)
            s += __shfl_down(s, off, 64);
        if (lane == 0) zred[wv16] = s;
    }

    // ---- phase B: out = X.u / Z, X from registers (zero new X traffic) ----
#pragma unroll
    for (int j = 0; j < 2; ++j)
#pragma unroll
        for (int o = 0; o < OO; ++o) acc[j][o] = 0.f;

#pragma unroll
    for (int c = 0; c < 8; ++c) {
        const float* wp = sWl + c * 32;
#pragma unroll
        for (int o = 0; o < OO; ++o) {
            const float4 wv = *(const float4*)(wp + o * DD);
#pragma unroll
            for (int j = 0; j < 2; ++j)
                acc[j][o] += xr[c][j].x * wv.x + xr[c][j].y * wv.y +
                             xr[c][j].z * wv.z + xr[c][j].w * wv.w;
        }
    }

#pragma unroll
    for (int j = 0; j < 2; ++j) {
#pragma unroll
        for (int o = 0; o < OO; ++o) {
            float v = acc[j][o];
            v += __shfl_down(v, 4, 8);
            v += __shfl_down(v, 2, 8);
            v += __shfl_down(v, 1, 8);
            if (l == 0) part[w][rb + j * 8 + g][o] = v;
        }
    }
    __syncthreads();

    if (tid < ROWS * OO) {
        const int row = tid / OO;
        const int o   = tid % OO;
        float v = part[0][row][o] + part[1][row][o] +
                  part[2][row][o] + part[3][row][o];
        out[((size_t)b * OO + o) * TT + (t0 + row)] = v / zred[o];
    }
}

// ---------------------------------------------------------------------------
// Fallback: proven R16 two-kernel path (119.4 us), used if coop launch fails.
// ---------------------------------------------------------------------------
template <bool FIRST>
__global__ __launch_bounds__(512) void gemm10_kernel(
    const float* __restrict__ X,
    const float* __restrict__ Wt,
    const float* __restrict__ bias,
    float* __restrict__ Y)
{
    __shared__ float4 sW4[OO * 256];
    __shared__ float  part[4][ROWS][OO];
    __shared__ float  zred[OO];

    const int b   = blockIdx.y;
    const int t0  = blockIdx.x * ROWS;
    const int tid = threadIdx.x;

    {
        const float4* src = (const float4*)(Wt + (FIRST ? 0 : (size_t)b * OO * TT));
#pragma unroll
        for (int c = 0; c < 5; ++c)
            sW4[c * 512 + tid] = src[c * 512 + tid];
    }
    __syncthreads();

    const int wv8  = tid >> 6;
    const int w    = wv8 & 3;
    const int half = wv8 >> 2;
    const int lane = tid & 63;
    const int l    = lane & 7;
    const int g    = lane >> 3;
    const int dofs = w * 256 + l * 4;
    const int rb   = half * 32;

    if (!FIRST) {
#pragma unroll
        for (int k = 0; k < 2; ++k) {
            const int o = wv8 + 8 * k;
            if (o < OO) {
                float s = 0.f;
#pragma unroll
                for (int q = 0; q < 4; ++q) {
                    const float4 v = sW4[o * 256 + lane * 4 + q];
                    s += v.x + v.y + v.z + v.w;
                }
#pragma unroll
                for (int off = 32; off > 0; off >>= 1)
                    s += __shfl_down(s, off, 64);
                if (lane == 0) zred[o] = s;
            }
        }
    }

    const float* xp[4];
#pragma unroll
    for (int j = 0; j < 4; ++j)
        xp[j] = X + ((size_t)b * TT + t0 + rb + g + 8 * j) * DD + dofs;
    const float* sWl = (const float*)sW4 + dofs;

    float acc[4][OO];
#pragma unroll
    for (int j = 0; j < 4; ++j)
#pragma unroll
        for (int o = 0; o < OO; ++o) acc[j][o] = 0.f;

    float4 x0[4], x1[4];
#pragma unroll
    for (int j = 0; j < 4; ++j) {
        x0[j] = *(const float4*)(xp[j]);
        x1[j] = *(const float4*)(xp[j] + 32);
    }

#pragma unroll 1
    for (int it = 0; it < 8; it += 2) {
        float4 c0[4];
#pragma unroll
        for (int j = 0; j < 4; ++j) c0[j] = x0[j];
        if (it < 6) {
#pragma unroll
            for (int j = 0; j < 4; ++j)
                x0[j] = *(const float4*)(xp[j] + (it + 2) * 32);
        }
        {
            const float* wp = sWl + it * 32;
#pragma unroll
            for (int o = 0; o < OO; ++o) {
                const float4 wv = *(const float4*)(wp + o * DD);
#pragma unroll
                for (int j = 0; j < 4; ++j)
                    acc[j][o] += c0[j].x * wv.x + c0[j].y * wv.y +
                                 c0[j].z * wv.z + c0[j].w * wv.w;
            }
        }
#pragma unroll
        for (int j = 0; j < 4; ++j) c0[j] = x1[j];
        if (it < 5) {
#pragma unroll
            for (int j = 0; j < 4; ++j)
                x1[j] = *(const float4*)(xp[j] + (it + 3) * 32);
        }
        {
            const float* wp = sWl + (it + 1) * 32;
#pragma unroll
            for (int o = 0; o < OO; ++o) {
                const float4 wv = *(const float4*)(wp + o * DD);
#pragma unroll
                for (int j = 0; j < 4; ++j)
                    acc[j][o] += c0[j].x * wv.x + c0[j].y * wv.y +
                                 c0[j].z * wv.z + c0[j].w * wv.w;
            }
        }
    }

#pragma unroll
    for (int j = 0; j < 4; ++j) {
#pragma unroll
        for (int o = 0; o < OO; ++o) {
            float v = acc[j][o];
            v += __shfl_down(v, 4, 8);
            v += __shfl_down(v, 2, 8);
            v += __shfl_down(v, 1, 8);
            if (l == 0) part[w][rb + j * 8 + g][o] = v;
        }
    }
    __syncthreads();

    for (int idx = tid; idx < ROWS * OO; idx += 512) {
        const int row = idx / OO;
        const int o   = idx % OO;
        float v = part[0][row][o] + part[1][row][o] +
                  part[2][row][o] + part[3][row][o];
        if (FIRST) {
            Y[((size_t)b * OO + o) * TT + (t0 + row)] =
                __expf((v + bias[o]) * (1.0f / OO));
        } else {
            Y[((size_t)b * OO + o) * TT + (t0 + row)] = v / zred[o];
        }
    }
}

extern "C" void kernel_launch(void* const* d_in, const int* in_sizes, int n_in,
                              void* d_out, int out_size, void* d_ws, size_t ws_size,
                              hipStream_t stream)
{
    const float* logits = (const float*)d_in[0];
    // d_in[1] = decision — unused by the forward math
    const float* W    = (const float*)d_in[2];
    const float* bias = (const float*)d_in[3];
    float* out = (float*)d_out;

    unsigned* flags = (unsigned*)d_ws;              // 256 words (poisoned/iter)
    float*    u     = (float*)d_ws + 1024;          // 4 KB offset; 655 KB slab

    dim3 grid(TT / ROWS, BB);       // (16,16) = 256 blocks = 1/CU
    dim3 blockF(1024);

    void* args[] = { (void*)&logits, (void*)&W, (void*)&bias,
                     (void*)&out, (void*)&u, (void*)&flags };
    hipError_t err = hipLaunchCooperativeKernel(
        (const void*)fused_persist, grid, blockF, args, 0, stream);

    if (err != hipSuccess) {
        (void)hipGetLastError();
        dim3 block(512);
        gemm10_kernel<true><<<grid, block, 0, stream>>>(logits, W, bias, u);
        gemm10_kernel<false><<<grid, block, 0, stream>>>(logits, u, nullptr, out);
    }
}

// Round 7
// 117.248 us; speedup vs baseline: 5.9669x; 5.9669x over previous
//
#include <hip/hip_runtime.h>

// Problem constants (reference: B,T,D,O = 16,1024,1024,10; T==D required)
#define BB 16
#define TT 1024
#define DD 1024
#define OO 10
#define ROWS 64

// ---------------------------------------------------------------------------
// R20 (this): R16 two-kernel structure (proven 119.4us) with ONE change:
// 16 waves per 64-row block (1024 threads, 2 rows/thread) instead of 8
// (512 threads, 4 rows/thread). Mechanism: pass1 (HBM-fed) and pass2
// (L3-fed) both run exactly ~18.6us -> neither is data-path-bound; waves
// stall on vmcnt each chunk-step (VALU-issue model ~4.3us). Doubling
// independent wave contexts per CU (8 -> 16) halves each wave's exposed
// latency share. Per-block amortization (ROWS=64, one 40KB staging, one
// barrier) is UNCHANGED — this is not R13 (which halved ROWS). Working set
// ~55 VGPR (acc[2][10]+4xfloat4 prefetch+addressing) fits even the
// compiler's worst-case 64-reg cap BY CONSTRUCTION -> no spill possible.
// FMA/reduction order per row identical to R16 -> bitwise-same absmax.
//
// REFUTED AS A CLASS: register-persistent X (R17 cap128/spill, R18
// launch_bounds ignored/spill, R19 cap64/spill — hipcc always targets
// max occupancy and spills persistent tiles; launch_bounds 2nd arg
// unreliable). Also refuted: grid.sync fusion (R8/R15: ~45us/sync),
// ws-avoidance (R15: 2x41us 256MiB poison fills are UNCONDITIONAL = 82us
// harness floor), per-chunk LDS staging barriers (R6), per-block softmax
// fold (R9), non-temporal X loads (R11), depth-4 prefetch banks (R12),
// ROWS=32 8-wave split (R13), 16-lane/256B chunks + ROWS=16 (R14).
//
// Ideal-arithmetic context: pass floor ~10.6us each (64MB @ 6.3TB/s);
// measured 18.6 each. If 16 waves doesn't move it, the 3.4TB/s plateau is
// wave-count-independent -> structural; revert to R16 and stop.
// ---------------------------------------------------------------------------
template <bool FIRST>
__global__ __launch_bounds__(1024) void gemm10_kernel(
    const float* __restrict__ X,     // (B,T,D) logits
    const float* __restrict__ Wt,    // FIRST: W (O,D); else u (B,O,T)
    const float* __restrict__ bias,  // FIRST only
    float* __restrict__ Y)           // FIRST: u (B,O,T); else out (B,O,T)
{
    __shared__ float4 sW4[OO * 256];      // 40 KB operand ([o][t4])
    __shared__ float  part[4][ROWS][OO];  // 10 KB
    __shared__ float  zred[OO];           // 40 B (pass2: softmax denom)

    const int b   = blockIdx.y;
    const int t0  = blockIdx.x * ROWS;
    const int tid = threadIdx.x;          // 0..1023

    // ---- stage operand -> LDS (2560 float4, contiguous, coalesced) ----
    {
        const float4* src = (const float4*)(Wt + (FIRST ? 0 : (size_t)b * OO * TT));
        for (int idx = tid; idx < OO * 256; idx += 1024)
            sW4[idx] = src[idx];
    }
    __syncthreads();

    const int wv16 = tid >> 6;       // wave 0..15
    const int w    = wv16 & 3;       // d quarter
    const int rq   = wv16 >> 2;      // row quarter (0..3) -> rows rq*16..+15
    const int lane = tid & 63;
    const int l    = lane & 7;       // d-slice within row (8 lanes x 16B)
    const int g    = lane >> 3;      // row group 0..7
    const int dofs = w * 256 + l * 4;
    const int rb   = rq * 16;

    if (!FIRST) {
        // Z[b,o] = sum_t u from the staged slab. Wave wv16 = o (0..9).
        // zred visibility at the epilogue is covered by the pre-epilogue
        // __syncthreads.
        if (wv16 < OO) {
            float s = 0.f;
#pragma unroll
            for (int q = 0; q < 4; ++q) {
                const float4 v = sW4[wv16 * 256 + lane * 4 + q];
                s += v.x + v.y + v.z + v.w;
            }
#pragma unroll
            for (int off = 32; off > 0; off >>= 1)
                s += __shfl_down(s, off, 64);
            if (lane == 0) zred[wv16] = s;
        }
    }

    // Thread's rows: t0 + rb + g + 8j, j = 0..1 (covers this quarter's 16).
    const float* xp[2];
#pragma unroll
    for (int j = 0; j < 2; ++j)
        xp[j] = X + ((size_t)b * TT + t0 + rb + g + 8 * j) * DD + dofs;
    const float* sWl = (const float*)sW4 + dofs;

    float acc[2][OO];
#pragma unroll
    for (int j = 0; j < 2; ++j)
#pragma unroll
        for (int o = 0; o < OO; ++o) acc[j][o] = 0.f;

    // 2-deep prefetch of the logits slices
    float4 x0[2], x1[2];
#pragma unroll
    for (int j = 0; j < 2; ++j) {
        x0[j] = *(const float4*)(xp[j]);
        x1[j] = *(const float4*)(xp[j] + 32);
    }

#pragma unroll 1
    for (int it = 0; it < 8; it += 2) {
        float4 c0[2];
#pragma unroll
        for (int j = 0; j < 2; ++j) c0[j] = x0[j];
        if (it < 6) {
#pragma unroll
            for (int j = 0; j < 2; ++j)
                x0[j] = *(const float4*)(xp[j] + (it + 2) * 32);
        }
        {
            const float* wp = sWl + it * 32;
#pragma unroll
            for (int o = 0; o < OO; ++o) {
                const float4 wv = *(const float4*)(wp + o * DD);
#pragma unroll
                for (int j = 0; j < 2; ++j)
                    acc[j][o] += c0[j].x * wv.x + c0[j].y * wv.y +
                                 c0[j].z * wv.z + c0[j].w * wv.w;
            }
        }
#pragma unroll
        for (int j = 0; j < 2; ++j) c0[j] = x1[j];
        if (it < 5) {
#pragma unroll
            for (int j = 0; j < 2; ++j)
                x1[j] = *(const float4*)(xp[j] + (it + 3) * 32);
        }
        {
            const float* wp = sWl + (it + 1) * 32;
#pragma unroll
            for (int o = 0; o < OO; ++o) {
                const float4 wv = *(const float4*)(wp + o * DD);
#pragma unroll
                for (int j = 0; j < 2; ++j)
                    acc[j][o] += c0[j].x * wv.x + c0[j].y * wv.y +
                                 c0[j].z * wv.z + c0[j].w * wv.w;
            }
        }
    }

    // 3-level reduction within each 8-lane group, then cross-wave via LDS.
    // Row quarters don't collide: quarter rq writes rows rb..rb+15 only.
#pragma unroll
    for (int j = 0; j < 2; ++j) {
#pragma unroll
        for (int o = 0; o < OO; ++o) {
            float v = acc[j][o];
            v += __shfl_down(v, 4, 8);
            v += __shfl_down(v, 2, 8);
            v += __shfl_down(v, 1, 8);
            if (l == 0) part[w][rb + j * 8 + g][o] = v;
        }
    }
    __syncthreads();

    // 64 rows x 10 o = 640 outputs; threads 0..639
    if (tid < ROWS * OO) {
        const int row = tid / OO;
        const int o   = tid % OO;
        float v = part[0][row][o] + part[1][row][o] +
                  part[2][row][o] + part[3][row][o];
        if (FIRST) {
            // u = exp((dot + bias)/O); |arg| < ~0.5 -> max-free exp is safe
            Y[((size_t)b * OO + o) * TT + (t0 + row)] =
                __expf((v + bias[o]) * (1.0f / OO));
        } else {
            Y[((size_t)b * OO + o) * TT + (t0 + row)] = v / zred[o];
        }
    }
}

extern "C" void kernel_launch(void* const* d_in, const int* in_sizes, int n_in,
                              void* d_out, int out_size, void* d_ws, size_t ws_size,
                              hipStream_t stream)
{
    const float* logits = (const float*)d_in[0];
    // d_in[1] = decision — unused by the forward math
    const float* W    = (const float*)d_in[2];
    const float* bias = (const float*)d_in[3];
    float* out = (float*)d_out;
    float* u   = (float*)d_ws;      // B*O*T floats = 655 KB

    dim3 grid(TT / ROWS, BB);       // (16, 16) = 256 blocks = 1/CU
    // K1: u = exp((X.W^T + b)/O)   (kernel boundary = fence)
    gemm10_kernel<true><<<grid, 1024, 0, stream>>>(logits, W, bias, u);
    // K3: Z computed in-block from the staged slab; out = (X.u) / Z
    gemm10_kernel<false><<<grid, 1024, 0, stream>>>(logits, u, nullptr, out);
}